// Round 10
// baseline (886.301 us; speedup 1.0000x reference)
//
#include <hip/hip_runtime.h>

#define TT    512
#define HH    64
#define NB    2                  // batches per block
#define NBLK  (1024 / NB)        // 512 blocks -> 2 blocks/CU co-resident
#define HP    72                 // h^T pitch in f16

typedef _Float16 f16x8 __attribute__((ext_vector_type(8)));
typedef _Float16 f16x4 __attribute__((ext_vector_type(4)));
typedef float    f32x4 __attribute__((ext_vector_type(4)));

__device__ __forceinline__ float sigmoidf_(float x) {
    return 1.0f / (1.0f + __expf(-x));
}
__device__ __forceinline__ float tanhf_(float x) {
    return 1.0f - 2.0f / (1.0f + __expf(2.0f * x));
}

// 512 blocks x 512 threads (8 waves); 2 blocks co-resident per CU (the round-10
// change: r9 had 1 block/CU and both pipes <50% -> latency-bound; two
// independent recurrences per CU fill each other's barrier/chain stalls).
// Block owns NB=2 batches (cols 0..1 of the 16-col MFMA tile; cols 2..15 are
// garbage — MFMA columns are independent, so junk never contaminates real ones).
// Group A = waves 0-3 (layer 1), group C = waves 4-7 (layer 2, fused K=128
// matvec over [h1; h2]). Wave w of a group owns M-tiles {w,w+4,w+8,w+12}
// (i,f,g,o of units [16w,16w+16) in one lane's accumulators); cell transpose
// -> 1 cell/lane pointwise. One barrier per tick, ticks 0..TT:
//   A (t<TT): g1(t) = b1 + W_ih0 x(t) + W_hh0 h1(t-1) -> h1(t) -> h1T[t&1]
//   C (t>=1): g2 = b2 + W_ih1 h1(t-1) + W_hh1 h2(t-2)  -> h2(t-1) -> h2T[t&1]
// Precision: f16 weights/h-hop, fp32 accum/bias/pointwise/c (r7/r9: 3.9e-3).
// Lessons kept: no cross-block handoff (r8: 4x regression), no min-waves
// clamp (r2: spill), wreg-in-registers + MFMA + 1-cell/lane pointwise.
__global__ __launch_bounds__(512) void lstm_mfma(
    const float* __restrict__ x,
    const float* __restrict__ w_ih0, const float* __restrict__ w_hh0,
    const float* __restrict__ b_ih0, const float* __restrict__ b_hh0,
    const float* __restrict__ w_ih1, const float* __restrict__ w_hh1,
    const float* __restrict__ b_ih1, const float* __restrict__ b_hh1,
    const float* __restrict__ w_out, const float* __restrict__ b_out,
    float* __restrict__ out)
{
    __shared__ __align__(16) _Float16 h1T[2][16 * HP];  // h1^T [col][unit] f16
    __shared__ __align__(16) _Float16 h2T[2][16 * HP];  // h2^T
    __shared__ float xs[TT * 3 * NB];                   // x [t][d][b] fp32
    __shared__ __align__(16) f32x4 cellA[4][64];        // A gate transpose
    __shared__ __align__(16) f32x4 cellC[4][64];        // C gate transpose
    __shared__ __align__(16) float h2f[16 * 68];        // final h2 fp32
    __shared__ float lg[NB][4];

    const int tid   = threadIdx.x;
    const int group = tid >> 8;          // 0 = A (layer 1), 1 = C (layer 2)
    const int w     = (tid >> 6) & 3;    // wave-in-group
    const int lane  = tid & 63;
    const int quad  = lane >> 4;
    const int n     = lane & 15;         // MFMA column
    const int b0    = blockIdx.x * NB;

    const int cu    = lane >> 2;                      // unit after transpose
    const int cb    = lane & 3;                       // col after transpose (0..1 real)
    const int rdslot = lane ^ ((lane >> 4) << 2);     // XOR-swizzled cell slot

    // ---- persistent weight fragments ----
    f16x8 whh[4][2], wih[4][2], axf[4];
    f32x4 biasf[4];
    #pragma unroll
    for (int g_ = 0; g_ < 4; ++g_) {
        const int arow = 16 * w + 64 * g_ + n;        // A-frag row m = lane&15
        const float* ph = (group == 0) ? (w_hh0 + arow * HH) : (w_hh1 + arow * HH);
        const float* pi = w_ih1 + arow * HH;
        #pragma unroll
        for (int k0 = 0; k0 < 2; ++k0) {
            #pragma unroll
            for (int j = 0; j < 8; ++j) {
                whh[g_][k0][j] = (_Float16)ph[quad * 8 + 32 * k0 + j];
                wih[g_][k0][j] = (group == 1) ? (_Float16)pi[quad * 8 + 32 * k0 + j]
                                              : (_Float16)0.f;
            }
        }
        #pragma unroll
        for (int r = 0; r < 4; ++r) {                 // C/D row = quad*4 + r
            const int crow = 16 * w + 64 * g_ + quad * 4 + r;
            biasf[g_][r] = (group == 0) ? (b_ih0[crow] + b_hh0[crow])
                                        : (b_ih1[crow] + b_hh1[crow]);
        }
        f16x8 ax;
        #pragma unroll
        for (int j = 0; j < 8; ++j) ax[j] = (_Float16)0.f;
        if (group == 0 && quad == 0) {                // K=3 x-transform
            ax[0] = (_Float16)w_ih0[arow * 3 + 0];
            ax[1] = (_Float16)w_ih0[arow * 3 + 1];
            ax[2] = (_Float16)w_ih0[arow * 3 + 2];
        }
        axf[g_] = ax;
    }

    // ---- LDS init ----
    for (int i = tid; i < 1152; i += 512) {
        ((int*)h1T)[i] = 0;
        ((int*)h2T)[i] = 0;
    }
    for (int i = tid; i < TT * 3 * NB; i += 512) {
        const int t = i / (3 * NB), rem = i - t * (3 * NB);
        const int d = rem >> 1, b = rem & 1;          // xs[t][d][b]
        xs[i] = x[(size_t)(b0 + b) * (TT * 3) + t * 3 + d];
    }
    __syncthreads();

    float creg = 0.f;    // A: c1 of (unit 16w+cu, col cb); C: c2 (cb>=2 junk, unused)

    for (int t = 0; t <= TT; ++t) {
        if (group == 0) {
            if (t < TT) {
                f16x8 bx;
                #pragma unroll
                for (int j = 0; j < 8; ++j) bx[j] = (_Float16)0.f;
                if (quad == 0) {
                    const float* xp = xs + t * 6 + (lane & 1);
                    bx[0] = (_Float16)xp[0];
                    bx[1] = (_Float16)xp[2];
                    bx[2] = (_Float16)xp[4];
                }
                const _Float16* hsrc = h1T[(t + 1) & 1];
                const f16x8 bh0 = *(const f16x8*)(hsrc + n * HP + quad * 8);
                const f16x8 bh1 = *(const f16x8*)(hsrc + n * HP + quad * 8 + 32);
                f32x4 acc[4];
                #pragma unroll
                for (int g_ = 0; g_ < 4; ++g_) {
                    f32x4 a = __builtin_amdgcn_mfma_f32_16x16x32_f16(axf[g_], bx, biasf[g_], 0, 0, 0);
                    a = __builtin_amdgcn_mfma_f32_16x16x32_f16(whh[g_][0], bh0, a, 0, 0, 0);
                    a = __builtin_amdgcn_mfma_f32_16x16x32_f16(whh[g_][1], bh1, a, 0, 0, 0);
                    acc[g_] = a;
                }
                if (n < NB) {
                    #pragma unroll
                    for (int r = 0; r < 4; ++r) {
                        const int slot = (16 * quad + 4 * r + n) ^ (quad << 2);
                        f32x4 v = {acc[0][r], acc[1][r], acc[2][r], acc[3][r]};
                        cellA[w][slot] = v;
                    }
                }
                const f32x4 gate = cellA[w][rdslot];   // cb>=2 lanes read junk (harmless)
                const float is = sigmoidf_(gate[0]);
                const float fs = sigmoidf_(gate[1]);
                const float gt = tanhf_(gate[2]);
                const float os = sigmoidf_(gate[3]);
                creg = fs * creg + is * gt;
                h1T[t & 1][cb * HP + 16 * w + cu] = (_Float16)(os * tanhf_(creg));
            }
        } else {
            if (t >= 1) {
                // fused K=128 matvec over [h1(t-1); h2(t-2)]
                const _Float16* h1src = h1T[(t + 1) & 1];
                const _Float16* h2src = h2T[(t + 1) & 1];
                const f16x8 b10 = *(const f16x8*)(h1src + n * HP + quad * 8);
                const f16x8 b11 = *(const f16x8*)(h1src + n * HP + quad * 8 + 32);
                const f16x8 b20 = *(const f16x8*)(h2src + n * HP + quad * 8);
                const f16x8 b21 = *(const f16x8*)(h2src + n * HP + quad * 8 + 32);
                f32x4 acc[4];
                #pragma unroll
                for (int g_ = 0; g_ < 4; ++g_) {
                    f32x4 a = __builtin_amdgcn_mfma_f32_16x16x32_f16(wih[g_][0], b10, biasf[g_], 0, 0, 0);
                    a = __builtin_amdgcn_mfma_f32_16x16x32_f16(wih[g_][1], b11, a, 0, 0, 0);
                    a = __builtin_amdgcn_mfma_f32_16x16x32_f16(whh[g_][0], b20, a, 0, 0, 0);
                    a = __builtin_amdgcn_mfma_f32_16x16x32_f16(whh[g_][1], b21, a, 0, 0, 0);
                    acc[g_] = a;
                }
                if (n < NB) {
                    #pragma unroll
                    for (int r = 0; r < 4; ++r) {
                        const int slot = (16 * quad + 4 * r + n) ^ (quad << 2);
                        f32x4 v = {acc[0][r], acc[1][r], acc[2][r], acc[3][r]};
                        cellC[w][slot] = v;
                    }
                }
                const f32x4 gate = cellC[w][rdslot];
                const float is = sigmoidf_(gate[0]);
                const float fs = sigmoidf_(gate[1]);
                const float gt = tanhf_(gate[2]);
                const float os = sigmoidf_(gate[3]);
                creg = fs * creg + is * gt;
                const float h = os * tanhf_(creg);
                h2T[t & 1][cb * HP + 16 * w + cu] = (_Float16)h;   // h2(t-1)
                if (t == TT) h2f[cb * 68 + 16 * w + cu] = h;       // h2(TT-1) fp32
            }
        }
        __syncthreads();
    }

    // ---- epilogue: logits + softmax on fp32 h2 (NB=2 real batches) ----
    if (tid < 8) {
        const int b = tid & 1, o = tid >> 1;
        float acc = b_out[o];
        #pragma unroll
        for (int j = 0; j < HH; ++j)
            acc = fmaf(w_out[o * HH + j], h2f[b * 68 + j], acc);
        lg[b][o] = acc;
    }
    __syncthreads();
    if (tid < NB) {
        const int b = tid;
        const float l0 = lg[b][0], l1 = lg[b][1], l2 = lg[b][2], l3 = lg[b][3];
        const float m  = fmaxf(fmaxf(l0, l1), fmaxf(l2, l3));
        const float e0 = __expf(l0 - m), e1 = __expf(l1 - m);
        const float e2 = __expf(l2 - m), e3 = __expf(l3 - m);
        const float sum = 1.0f / (e0 + e1 + e2 + e3);
        out[(b0 + b) * 4 + 0] = e0 * sum;
        out[(b0 + b) * 4 + 1] = e1 * sum;
        out[(b0 + b) * 4 + 2] = e2 * sum;
        out[(b0 + b) * 4 + 3] = e3 * sum;
    }
}

extern "C" void kernel_launch(void* const* d_in, const int* in_sizes, int n_in,
                              void* d_out, int out_size, void* d_ws, size_t ws_size,
                              hipStream_t stream) {
    const float* x     = (const float*)d_in[0];
    const float* w_ih0 = (const float*)d_in[1];
    const float* w_hh0 = (const float*)d_in[2];
    const float* b_ih0 = (const float*)d_in[3];
    const float* b_hh0 = (const float*)d_in[4];
    const float* w_ih1 = (const float*)d_in[5];
    const float* w_hh1 = (const float*)d_in[6];
    const float* b_ih1 = (const float*)d_in[7];
    const float* b_hh1 = (const float*)d_in[8];
    const float* w_out = (const float*)d_in[9];
    const float* b_out = (const float*)d_in[10];
    float* out = (float*)d_out;

    hipLaunchKernelGGL(lstm_mfma, dim3(NBLK), dim3(512), 0, stream,
                       x, w_ih0, w_hh0, b_ih0, b_hh0,
                       w_ih1, w_hh1, b_ih1, b_hh1,
                       w_out, b_out, out);
}

// Round 11
// 874.218 us; speedup vs baseline: 1.0138x; 1.0138x over previous
//
#include <hip/hip_runtime.h>

#define TT    512
#define HH    64
#define NB    2                  // batches per block
#define NBLK  (1024 / NB)        // 512 blocks -> target 2 blocks/CU
#define HP    72                 // h^T pitch in f16

typedef _Float16 f16x8 __attribute__((ext_vector_type(8)));
typedef _Float16 f16x4 __attribute__((ext_vector_type(4)));
typedef float    f32x4 __attribute__((ext_vector_type(4)));

__device__ __forceinline__ float sigmoidf_(float x) {
    return 1.0f / (1.0f + __expf(-x));
}
__device__ __forceinline__ float tanhf_(float x) {
    return 1.0f - 2.0f / (1.0f + __expf(2.0f * x));
}

// 512 blocks x 512 threads (8 waves); TARGET: 2 blocks co-resident per CU.
// r10 lesson: multi-WG packing per CU is limited to a ~64 KiB LDS pool
// (r2: 2x19.9KB packed; r10: 2x34.3KB did NOT). This round's only change vs
// r10: x slice stored as f16 (identical numerics — x was cast to f16 per tick
// anyway), dropping block LDS 34.3 -> ~27.9 KB so two blocks fit the pool.
// Block owns NB=2 batches (cols 0..1 of the 16-col MFMA tile; other cols are
// independent junk). Group A = waves 0-3 (layer 1), group C = waves 4-7
// (layer 2, fused K=128 over [h1; h2]). Wave w of a group owns M-tiles
// {w,w+4,w+8,w+12}; cell transpose -> 1 cell/lane pointwise. 1 barrier/tick:
//   A (t<TT): g1(t) = b1 + W_ih0 x(t) + W_hh0 h1(t-1) -> h1(t) -> h1T[t&1]
//   C (t>=1): g2 = b2 + W_ih1 h1(t-1) + W_hh1 h2(t-2)  -> h2(t-1) -> h2T[t&1]
// Precision: f16 weights/h-hop/x, fp32 accum/bias/pointwise/c (3.9e-3).
// Lessons kept: no cross-block handoff (r8), no min-waves clamp (r2),
// VGPR<=~96 so 4 waves/SIMD fit (384<=512).
__global__ __launch_bounds__(512) void lstm_mfma(
    const float* __restrict__ x,
    const float* __restrict__ w_ih0, const float* __restrict__ w_hh0,
    const float* __restrict__ b_ih0, const float* __restrict__ b_hh0,
    const float* __restrict__ w_ih1, const float* __restrict__ w_hh1,
    const float* __restrict__ b_ih1, const float* __restrict__ b_hh1,
    const float* __restrict__ w_out, const float* __restrict__ b_out,
    float* __restrict__ out)
{
    __shared__ __align__(16) _Float16 h1T[2][16 * HP];  // h1^T [col][unit] f16
    __shared__ __align__(16) _Float16 h2T[2][16 * HP];  // h2^T
    __shared__ _Float16 xs[TT * 3 * NB];                // x [t][d][b] f16 (6 KB)
    __shared__ __align__(16) f32x4 cellA[4][64];        // A gate transpose
    __shared__ __align__(16) f32x4 cellC[4][64];        // C gate transpose
    __shared__ __align__(16) float h2f[16 * 68];        // final h2 fp32
    __shared__ float lg[NB][4];

    const int tid   = threadIdx.x;
    const int group = tid >> 8;          // 0 = A (layer 1), 1 = C (layer 2)
    const int w     = (tid >> 6) & 3;    // wave-in-group
    const int lane  = tid & 63;
    const int quad  = lane >> 4;
    const int n     = lane & 15;         // MFMA column
    const int b0    = blockIdx.x * NB;

    const int cu    = lane >> 2;                      // unit after transpose
    const int cb    = lane & 3;                       // col after transpose (0..1 real)
    const int rdslot = lane ^ ((lane >> 4) << 2);     // XOR-swizzled cell slot

    // ---- persistent weight fragments ----
    f16x8 whh[4][2], wih[4][2], axf[4];
    f32x4 biasf[4];
    #pragma unroll
    for (int g_ = 0; g_ < 4; ++g_) {
        const int arow = 16 * w + 64 * g_ + n;        // A-frag row m = lane&15
        const float* ph = (group == 0) ? (w_hh0 + arow * HH) : (w_hh1 + arow * HH);
        const float* pi = w_ih1 + arow * HH;
        #pragma unroll
        for (int k0 = 0; k0 < 2; ++k0) {
            #pragma unroll
            for (int j = 0; j < 8; ++j) {
                whh[g_][k0][j] = (_Float16)ph[quad * 8 + 32 * k0 + j];
                wih[g_][k0][j] = (group == 1) ? (_Float16)pi[quad * 8 + 32 * k0 + j]
                                              : (_Float16)0.f;
            }
        }
        #pragma unroll
        for (int r = 0; r < 4; ++r) {                 // C/D row = quad*4 + r
            const int crow = 16 * w + 64 * g_ + quad * 4 + r;
            biasf[g_][r] = (group == 0) ? (b_ih0[crow] + b_hh0[crow])
                                        : (b_ih1[crow] + b_hh1[crow]);
        }
        f16x8 ax;
        #pragma unroll
        for (int j = 0; j < 8; ++j) ax[j] = (_Float16)0.f;
        if (group == 0 && quad == 0) {                // K=3 x-transform
            ax[0] = (_Float16)w_ih0[arow * 3 + 0];
            ax[1] = (_Float16)w_ih0[arow * 3 + 1];
            ax[2] = (_Float16)w_ih0[arow * 3 + 2];
        }
        axf[g_] = ax;
    }

    // ---- LDS init ----
    for (int i = tid; i < 1152; i += 512) {
        ((int*)h1T)[i] = 0;
        ((int*)h2T)[i] = 0;
    }
    for (int i = tid; i < TT * 3 * NB; i += 512) {
        const int t = i / (3 * NB), rem = i - t * (3 * NB);
        const int d = rem >> 1, b = rem & 1;          // xs[t][d][b]
        xs[i] = (_Float16)x[(size_t)(b0 + b) * (TT * 3) + t * 3 + d];
    }
    __syncthreads();

    float creg = 0.f;    // A: c1 of (unit 16w+cu, col cb); C: c2 (cb>=2 junk)

    for (int t = 0; t <= TT; ++t) {
        if (group == 0) {
            if (t < TT) {
                f16x8 bx;
                #pragma unroll
                for (int j = 0; j < 8; ++j) bx[j] = (_Float16)0.f;
                if (quad == 0) {
                    const _Float16* xp = xs + t * 6 + (lane & 1);
                    bx[0] = xp[0];
                    bx[1] = xp[2];
                    bx[2] = xp[4];
                }
                const _Float16* hsrc = h1T[(t + 1) & 1];
                const f16x8 bh0 = *(const f16x8*)(hsrc + n * HP + quad * 8);
                const f16x8 bh1 = *(const f16x8*)(hsrc + n * HP + quad * 8 + 32);
                f32x4 acc[4];
                #pragma unroll
                for (int g_ = 0; g_ < 4; ++g_) {
                    f32x4 a = __builtin_amdgcn_mfma_f32_16x16x32_f16(axf[g_], bx, biasf[g_], 0, 0, 0);
                    a = __builtin_amdgcn_mfma_f32_16x16x32_f16(whh[g_][0], bh0, a, 0, 0, 0);
                    a = __builtin_amdgcn_mfma_f32_16x16x32_f16(whh[g_][1], bh1, a, 0, 0, 0);
                    acc[g_] = a;
                }
                if (n < NB) {
                    #pragma unroll
                    for (int r = 0; r < 4; ++r) {
                        const int slot = (16 * quad + 4 * r + n) ^ (quad << 2);
                        f32x4 v = {acc[0][r], acc[1][r], acc[2][r], acc[3][r]};
                        cellA[w][slot] = v;
                    }
                }
                const f32x4 gate = cellA[w][rdslot];   // cb>=2 lanes read junk
                const float is = sigmoidf_(gate[0]);
                const float fs = sigmoidf_(gate[1]);
                const float gt = tanhf_(gate[2]);
                const float os = sigmoidf_(gate[3]);
                creg = fs * creg + is * gt;
                h1T[t & 1][cb * HP + 16 * w + cu] = (_Float16)(os * tanhf_(creg));
            }
        } else {
            if (t >= 1) {
                // fused K=128 matvec over [h1(t-1); h2(t-2)]
                const _Float16* h1src = h1T[(t + 1) & 1];
                const _Float16* h2src = h2T[(t + 1) & 1];
                const f16x8 b10 = *(const f16x8*)(h1src + n * HP + quad * 8);
                const f16x8 b11 = *(const f16x8*)(h1src + n * HP + quad * 8 + 32);
                const f16x8 b20 = *(const f16x8*)(h2src + n * HP + quad * 8);
                const f16x8 b21 = *(const f16x8*)(h2src + n * HP + quad * 8 + 32);
                f32x4 acc[4];
                #pragma unroll
                for (int g_ = 0; g_ < 4; ++g_) {
                    f32x4 a = __builtin_amdgcn_mfma_f32_16x16x32_f16(wih[g_][0], b10, biasf[g_], 0, 0, 0);
                    a = __builtin_amdgcn_mfma_f32_16x16x32_f16(wih[g_][1], b11, a, 0, 0, 0);
                    a = __builtin_amdgcn_mfma_f32_16x16x32_f16(whh[g_][0], b20, a, 0, 0, 0);
                    a = __builtin_amdgcn_mfma_f32_16x16x32_f16(whh[g_][1], b21, a, 0, 0, 0);
                    acc[g_] = a;
                }
                if (n < NB) {
                    #pragma unroll
                    for (int r = 0; r < 4; ++r) {
                        const int slot = (16 * quad + 4 * r + n) ^ (quad << 2);
                        f32x4 v = {acc[0][r], acc[1][r], acc[2][r], acc[3][r]};
                        cellC[w][slot] = v;
                    }
                }
                const f32x4 gate = cellC[w][rdslot];
                const float is = sigmoidf_(gate[0]);
                const float fs = sigmoidf_(gate[1]);
                const float gt = tanhf_(gate[2]);
                const float os = sigmoidf_(gate[3]);
                creg = fs * creg + is * gt;
                const float h = os * tanhf_(creg);
                h2T[t & 1][cb * HP + 16 * w + cu] = (_Float16)h;   // h2(t-1)
                if (t == TT) h2f[cb * 68 + 16 * w + cu] = h;       // h2(TT-1) fp32
            }
        }
        __syncthreads();
    }

    // ---- epilogue: logits + softmax on fp32 h2 (NB=2 real batches) ----
    if (tid < 8) {
        const int b = tid & 1, o = tid >> 1;
        float acc = b_out[o];
        #pragma unroll
        for (int j = 0; j < HH; ++j)
            acc = fmaf(w_out[o * HH + j], h2f[b * 68 + j], acc);
        lg[b][o] = acc;
    }
    __syncthreads();
    if (tid < NB) {
        const int b = tid;
        const float l0 = lg[b][0], l1 = lg[b][1], l2 = lg[b][2], l3 = lg[b][3];
        const float m  = fmaxf(fmaxf(l0, l1), fmaxf(l2, l3));
        const float e0 = __expf(l0 - m), e1 = __expf(l1 - m);
        const float e2 = __expf(l2 - m), e3 = __expf(l3 - m);
        const float sum = 1.0f / (e0 + e1 + e2 + e3);
        out[(b0 + b) * 4 + 0] = e0 * sum;
        out[(b0 + b) * 4 + 1] = e1 * sum;
        out[(b0 + b) * 4 + 2] = e2 * sum;
        out[(b0 + b) * 4 + 3] = e3 * sum;
    }
}

extern "C" void kernel_launch(void* const* d_in, const int* in_sizes, int n_in,
                              void* d_out, int out_size, void* d_ws, size_t ws_size,
                              hipStream_t stream) {
    const float* x     = (const float*)d_in[0];
    const float* w_ih0 = (const float*)d_in[1];
    const float* w_hh0 = (const float*)d_in[2];
    const float* b_ih0 = (const float*)d_in[3];
    const float* b_hh0 = (const float*)d_in[4];
    const float* w_ih1 = (const float*)d_in[5];
    const float* w_hh1 = (const float*)d_in[6];
    const float* b_ih1 = (const float*)d_in[7];
    const float* b_hh1 = (const float*)d_in[8];
    const float* w_out = (const float*)d_in[9];
    const float* b_out = (const float*)d_in[10];
    float* out = (float*)d_out;

    hipLaunchKernelGGL(lstm_mfma, dim3(NBLK), dim3(512), 0, stream,
                       x, w_ih0, w_hh0, b_ih0, b_hh0,
                       w_ih1, w_hh1, b_ih1, b_hh1,
                       w_out, b_out, out);
}

// Round 12
// 767.196 us; speedup vs baseline: 1.1552x; 1.1395x over previous
//
#include <hip/hip_runtime.h>

#define TT    512
#define HH    64
#define NBH   2                  // batches per half-block
#define NBLK  256                // 256 blocks x 1024 threads; 4 batches/block
#define HP    72                 // h^T pitch in f16

typedef _Float16 f16x8 __attribute__((ext_vector_type(8)));
typedef float    f32x4 __attribute__((ext_vector_type(4)));

__device__ __forceinline__ float sigmoidf_(float x) {
    return 1.0f / (1.0f + __expf(-x));
}
__device__ __forceinline__ float tanhf_(float x) {
    return 1.0f - 2.0f / (1.0f + __expf(2.0f * x));
}

// 256 blocks x 1024 threads (16 waves) — TWO independent NB=2 recurrences
// ("halves") fused into one workgroup. r10/r11 lesson: the dispatcher would
// not co-schedule two 8-wave blocks per CU even at 27.5 KB LDS (occupancy
// pinned at 23.7%); a single 16-wave WG is under our control (r7: 12 waves +
// 77 KB worked). Wave i -> SIMD i&3, so each SIMD hosts {A0,C0,A1,C1}: four
// independent streams fill each other's MFMA/lgkm/transcendental stalls.
// Per half (identical to r11): group A = layer 1, group C = layer 2 (fused
// K=128 over [h1;h2]); wave w owns M-tiles {w,w+4,w+8,w+12} (i,f,g,o of units
// [16w,16w+16) in one lane's accs); cell transpose -> 1 cell/lane pointwise.
// One barrier per tick (all 16 waves, unconditional). Ticks 0..TT:
//   A (t<TT): g1(t) = b1 + W_ih0 x(t) + W_hh0 h1(t-1) -> h1(t)
//   C (t>=1): g2 = b2 + W_ih1 h1(t-1) + W_hh1 h2(t-2)  -> h2(t-1)
// Precision: f16 weights/h-hop/x, fp32 accum/bias/pointwise/c (3.9e-3).
// Lessons kept: no cross-block handoff (r8), no min-waves clamp (r2),
// VGPR must stay <=128 for 4 waves/SIMD (launch_bounds enforces).
__global__ __launch_bounds__(1024) void lstm_mfma(
    const float* __restrict__ x,
    const float* __restrict__ w_ih0, const float* __restrict__ w_hh0,
    const float* __restrict__ b_ih0, const float* __restrict__ b_hh0,
    const float* __restrict__ w_ih1, const float* __restrict__ w_hh1,
    const float* __restrict__ b_ih1, const float* __restrict__ b_hh1,
    const float* __restrict__ w_out, const float* __restrict__ b_out,
    float* __restrict__ out)
{
    __shared__ __align__(16) _Float16 h1T[2][2][16 * HP];  // [half][buf]
    __shared__ __align__(16) _Float16 h2T[2][2][16 * HP];
    __shared__ _Float16 xs[2][TT * 3 * NBH];               // [half] x f16
    __shared__ __align__(16) f32x4 cellA[2][4][64];        // [half][wave]
    __shared__ __align__(16) f32x4 cellC[2][4][64];
    __shared__ __align__(16) float h2f[2][16 * 68];        // final h2 fp32
    __shared__ float lg[2][NBH][4];

    const int tid   = threadIdx.x;
    const int half  = tid >> 9;          // 0/1: which recurrence
    const int group = (tid >> 8) & 1;    // 0 = A (layer 1), 1 = C (layer 2)
    const int w     = (tid >> 6) & 3;    // wave-in-group
    const int lane  = tid & 63;
    const int quad  = lane >> 4;
    const int n     = lane & 15;         // MFMA column
    const int b0    = blockIdx.x * 4 + half * NBH;

    const int cu    = lane >> 2;                      // unit after transpose
    const int cb    = lane & 3;                       // col after transpose (0..1 real)
    const int rdslot = lane ^ ((lane >> 4) << 2);     // XOR-swizzled cell slot

    // ---- persistent weight fragments (same for both halves) ----
    f16x8 whh[4][2], wih[4][2], axf[4];
    f32x4 biasf[4];
    #pragma unroll
    for (int g_ = 0; g_ < 4; ++g_) {
        const int arow = 16 * w + 64 * g_ + n;        // A-frag row m = lane&15
        const float* ph = (group == 0) ? (w_hh0 + arow * HH) : (w_hh1 + arow * HH);
        const float* pi = w_ih1 + arow * HH;
        #pragma unroll
        for (int k0 = 0; k0 < 2; ++k0) {
            #pragma unroll
            for (int j = 0; j < 8; ++j) {
                whh[g_][k0][j] = (_Float16)ph[quad * 8 + 32 * k0 + j];
                wih[g_][k0][j] = (group == 1) ? (_Float16)pi[quad * 8 + 32 * k0 + j]
                                              : (_Float16)0.f;
            }
        }
        #pragma unroll
        for (int r = 0; r < 4; ++r) {                 // C/D row = quad*4 + r
            const int crow = 16 * w + 64 * g_ + quad * 4 + r;
            biasf[g_][r] = (group == 0) ? (b_ih0[crow] + b_hh0[crow])
                                        : (b_ih1[crow] + b_hh1[crow]);
        }
        f16x8 ax;
        #pragma unroll
        for (int j = 0; j < 8; ++j) ax[j] = (_Float16)0.f;
        if (group == 0 && quad == 0) {                // K=3 x-transform
            ax[0] = (_Float16)w_ih0[arow * 3 + 0];
            ax[1] = (_Float16)w_ih0[arow * 3 + 1];
            ax[2] = (_Float16)w_ih0[arow * 3 + 2];
        }
        axf[g_] = ax;
    }

    // ---- LDS init ----
    for (int i = tid; i < 2 * 2 * 1152 / 2; i += 1024) {   // 2304 ints per array set
        ((int*)h1T)[i] = 0;
        ((int*)h2T)[i] = 0;
    }
    {   // x preload: each half's slice, [t][d][b] f16
        const int htid = tid & 511;
        for (int i = htid; i < TT * 3 * NBH; i += 512) {
            const int t = i / (3 * NBH), rem = i - t * (3 * NBH);
            const int d = rem >> 1, b = rem & 1;
            xs[half][i] = (_Float16)x[(size_t)(b0 + b) * (TT * 3) + t * 3 + d];
        }
    }
    __syncthreads();

    float creg = 0.f;    // A: c1 of (unit 16w+cu, col cb); C: c2 (cb>=2 junk)

    for (int t = 0; t <= TT; ++t) {
        if (group == 0) {
            if (t < TT) {
                f16x8 bx;
                #pragma unroll
                for (int j = 0; j < 8; ++j) bx[j] = (_Float16)0.f;
                if (quad == 0) {
                    const _Float16* xp = xs[half] + t * 6 + (lane & 1);
                    bx[0] = xp[0];
                    bx[1] = xp[2];
                    bx[2] = xp[4];
                }
                const _Float16* hsrc = h1T[half][(t + 1) & 1];
                const f16x8 bh0 = *(const f16x8*)(hsrc + n * HP + quad * 8);
                const f16x8 bh1 = *(const f16x8*)(hsrc + n * HP + quad * 8 + 32);
                f32x4 acc[4];
                #pragma unroll
                for (int g_ = 0; g_ < 4; ++g_) {
                    f32x4 a = __builtin_amdgcn_mfma_f32_16x16x32_f16(axf[g_], bx, biasf[g_], 0, 0, 0);
                    a = __builtin_amdgcn_mfma_f32_16x16x32_f16(whh[g_][0], bh0, a, 0, 0, 0);
                    a = __builtin_amdgcn_mfma_f32_16x16x32_f16(whh[g_][1], bh1, a, 0, 0, 0);
                    acc[g_] = a;
                }
                if (n < NBH) {
                    #pragma unroll
                    for (int r = 0; r < 4; ++r) {
                        const int slot = (16 * quad + 4 * r + n) ^ (quad << 2);
                        f32x4 v = {acc[0][r], acc[1][r], acc[2][r], acc[3][r]};
                        cellA[half][w][slot] = v;
                    }
                }
                const f32x4 gate = cellA[half][w][rdslot];   // cb>=2 lanes: junk
                const float is = sigmoidf_(gate[0]);
                const float fs = sigmoidf_(gate[1]);
                const float gt = tanhf_(gate[2]);
                const float os = sigmoidf_(gate[3]);
                creg = fs * creg + is * gt;
                h1T[half][t & 1][cb * HP + 16 * w + cu] = (_Float16)(os * tanhf_(creg));
            }
        } else {
            if (t >= 1) {
                // fused K=128 matvec over [h1(t-1); h2(t-2)]
                const _Float16* h1src = h1T[half][(t + 1) & 1];
                const _Float16* h2src = h2T[half][(t + 1) & 1];
                const f16x8 b10 = *(const f16x8*)(h1src + n * HP + quad * 8);
                const f16x8 b11 = *(const f16x8*)(h1src + n * HP + quad * 8 + 32);
                const f16x8 b20 = *(const f16x8*)(h2src + n * HP + quad * 8);
                const f16x8 b21 = *(const f16x8*)(h2src + n * HP + quad * 8 + 32);
                f32x4 acc[4];
                #pragma unroll
                for (int g_ = 0; g_ < 4; ++g_) {
                    f32x4 a = __builtin_amdgcn_mfma_f32_16x16x32_f16(wih[g_][0], b10, biasf[g_], 0, 0, 0);
                    a = __builtin_amdgcn_mfma_f32_16x16x32_f16(wih[g_][1], b11, a, 0, 0, 0);
                    a = __builtin_amdgcn_mfma_f32_16x16x32_f16(whh[g_][0], b20, a, 0, 0, 0);
                    a = __builtin_amdgcn_mfma_f32_16x16x32_f16(whh[g_][1], b21, a, 0, 0, 0);
                    acc[g_] = a;
                }
                if (n < NBH) {
                    #pragma unroll
                    for (int r = 0; r < 4; ++r) {
                        const int slot = (16 * quad + 4 * r + n) ^ (quad << 2);
                        f32x4 v = {acc[0][r], acc[1][r], acc[2][r], acc[3][r]};
                        cellC[half][w][slot] = v;
                    }
                }
                const f32x4 gate = cellC[half][w][rdslot];
                const float is = sigmoidf_(gate[0]);
                const float fs = sigmoidf_(gate[1]);
                const float gt = tanhf_(gate[2]);
                const float os = sigmoidf_(gate[3]);
                creg = fs * creg + is * gt;
                const float h = os * tanhf_(creg);
                h2T[half][t & 1][cb * HP + 16 * w + cu] = (_Float16)h;   // h2(t-1)
                if (t == TT) h2f[half][cb * 68 + 16 * w + cu] = h;       // h2(TT-1)
            }
        }
        __syncthreads();
    }

    // ---- epilogue: logits + softmax per half (NBH=2 real batches) ----
    const int htid = tid & 511;
    if (htid < 8) {
        const int b = htid & 1, o = htid >> 1;
        float acc = b_out[o];
        #pragma unroll
        for (int j = 0; j < HH; ++j)
            acc = fmaf(w_out[o * HH + j], h2f[half][b * 68 + j], acc);
        lg[half][b][o] = acc;
    }
    __syncthreads();
    if (htid < NBH) {
        const int b = htid;
        const float l0 = lg[half][b][0], l1 = lg[half][b][1];
        const float l2 = lg[half][b][2], l3 = lg[half][b][3];
        const float m  = fmaxf(fmaxf(l0, l1), fmaxf(l2, l3));
        const float e0 = __expf(l0 - m), e1 = __expf(l1 - m);
        const float e2 = __expf(l2 - m), e3 = __expf(l3 - m);
        const float sum = 1.0f / (e0 + e1 + e2 + e3);
        out[(b0 + b) * 4 + 0] = e0 * sum;
        out[(b0 + b) * 4 + 1] = e1 * sum;
        out[(b0 + b) * 4 + 2] = e2 * sum;
        out[(b0 + b) * 4 + 3] = e3 * sum;
    }
}

extern "C" void kernel_launch(void* const* d_in, const int* in_sizes, int n_in,
                              void* d_out, int out_size, void* d_ws, size_t ws_size,
                              hipStream_t stream) {
    const float* x     = (const float*)d_in[0];
    const float* w_ih0 = (const float*)d_in[1];
    const float* w_hh0 = (const float*)d_in[2];
    const float* b_ih0 = (const float*)d_in[3];
    const float* b_hh0 = (const float*)d_in[4];
    const float* w_ih1 = (const float*)d_in[5];
    const float* w_hh1 = (const float*)d_in[6];
    const float* b_ih1 = (const float*)d_in[7];
    const float* b_hh1 = (const float*)d_in[8];
    const float* w_out = (const float*)d_in[9];
    const float* b_out = (const float*)d_in[10];
    float* out = (float*)d_out;

    hipLaunchKernelGGL(lstm_mfma, dim3(NBLK), dim3(1024), 0, stream,
                       x, w_ih0, w_hh0, b_ih0, b_hh0,
                       w_ih1, w_hh1, b_ih1, b_hh1,
                       w_out, b_out, out);
}

// Round 13
// 766.041 us; speedup vs baseline: 1.1570x; 1.0015x over previous
//
#include <hip/hip_runtime.h>

#define TT    512
#define HH    64
#define NBH   2                  // batches per half-block
#define NBLK  256                // 256 blocks x 1024 threads; 4 batches/block
#define HP    72                 // h^T pitch in f16

typedef _Float16 f16x8 __attribute__((ext_vector_type(8)));
typedef float    f32x4 __attribute__((ext_vector_type(4)));

__device__ __forceinline__ float sigmoidf_(float x) {
    return 1.0f / (1.0f + __expf(-x));
}
__device__ __forceinline__ float tanhf_(float x) {
    return 1.0f - 2.0f / (1.0f + __expf(2.0f * x));
}

// 256 blocks x 1024 threads (16 waves) — TWO independent NB=2 recurrences
// ("halves") fused into one workgroup (r12). Each SIMD hosts {A0,C0,A1,C1}:
// four independent streams fill each other's MFMA/lgkm/transcendental stalls.
// ROUND-13 FIX: __launch_bounds__(1024, 4) — 4 waves/EU -> VGPR cap 128.
// r12 omitted the min-waves arg; the compiler chose 64 VGPRs and SPILLED the
// ~96-VGPR working set (FETCH 4->47MB, WRITE 16KB->84MB of scratch traffic).
// This is the r2 lesson inverted: the 2nd launch_bounds arg must match the
// occupancy we actually want — too high spills (r2), absent under-allocates (r12).
// Per half: group A = layer 1, group C = layer 2 (fused K=128 over [h1;h2]);
// wave w owns M-tiles {w,w+4,w+8,w+12} (i,f,g,o of units [16w,16w+16) in one
// lane's accs); cell transpose -> 1 cell/lane pointwise. 1 barrier/tick:
//   A (t<TT): g1(t) = b1 + W_ih0 x(t) + W_hh0 h1(t-1) -> h1(t)
//   C (t>=1): g2 = b2 + W_ih1 h1(t-1) + W_hh1 h2(t-2)  -> h2(t-1)
// Precision: f16 weights/h-hop/x, fp32 accum/bias/pointwise/c (3.9e-3).
// Lessons kept: no cross-block handoff (r8), in-WG TLP not dispatcher TLP (r10/r11).
__global__ __launch_bounds__(1024, 4) void lstm_mfma(
    const float* __restrict__ x,
    const float* __restrict__ w_ih0, const float* __restrict__ w_hh0,
    const float* __restrict__ b_ih0, const float* __restrict__ b_hh0,
    const float* __restrict__ w_ih1, const float* __restrict__ w_hh1,
    const float* __restrict__ b_ih1, const float* __restrict__ b_hh1,
    const float* __restrict__ w_out, const float* __restrict__ b_out,
    float* __restrict__ out)
{
    __shared__ __align__(16) _Float16 h1T[2][2][16 * HP];  // [half][buf]
    __shared__ __align__(16) _Float16 h2T[2][2][16 * HP];
    __shared__ _Float16 xs[2][TT * 3 * NBH];               // [half] x f16
    __shared__ __align__(16) f32x4 cellA[2][4][64];        // [half][wave]
    __shared__ __align__(16) f32x4 cellC[2][4][64];
    __shared__ __align__(16) float h2f[2][16 * 68];        // final h2 fp32
    __shared__ float lg[2][NBH][4];

    const int tid   = threadIdx.x;
    const int half  = tid >> 9;          // 0/1: which recurrence
    const int group = (tid >> 8) & 1;    // 0 = A (layer 1), 1 = C (layer 2)
    const int w     = (tid >> 6) & 3;    // wave-in-group
    const int lane  = tid & 63;
    const int quad  = lane >> 4;
    const int n     = lane & 15;         // MFMA column
    const int b0    = blockIdx.x * 4 + half * NBH;

    const int cu    = lane >> 2;                      // unit after transpose
    const int cb    = lane & 3;                       // col after transpose (0..1 real)
    const int rdslot = lane ^ ((lane >> 4) << 2);     // XOR-swizzled cell slot

    // ---- persistent weight fragments (same for both halves) ----
    f16x8 whh[4][2], wih[4][2], axf[4];
    f32x4 biasf[4];
    #pragma unroll
    for (int g_ = 0; g_ < 4; ++g_) {
        const int arow = 16 * w + 64 * g_ + n;        // A-frag row m = lane&15
        const float* ph = (group == 0) ? (w_hh0 + arow * HH) : (w_hh1 + arow * HH);
        const float* pi = w_ih1 + arow * HH;
        #pragma unroll
        for (int k0 = 0; k0 < 2; ++k0) {
            #pragma unroll
            for (int j = 0; j < 8; ++j) {
                whh[g_][k0][j] = (_Float16)ph[quad * 8 + 32 * k0 + j];
                wih[g_][k0][j] = (group == 1) ? (_Float16)pi[quad * 8 + 32 * k0 + j]
                                              : (_Float16)0.f;
            }
        }
        #pragma unroll
        for (int r = 0; r < 4; ++r) {                 // C/D row = quad*4 + r
            const int crow = 16 * w + 64 * g_ + quad * 4 + r;
            biasf[g_][r] = (group == 0) ? (b_ih0[crow] + b_hh0[crow])
                                        : (b_ih1[crow] + b_hh1[crow]);
        }
        f16x8 ax;
        #pragma unroll
        for (int j = 0; j < 8; ++j) ax[j] = (_Float16)0.f;
        if (group == 0 && quad == 0) {                // K=3 x-transform
            ax[0] = (_Float16)w_ih0[arow * 3 + 0];
            ax[1] = (_Float16)w_ih0[arow * 3 + 1];
            ax[2] = (_Float16)w_ih0[arow * 3 + 2];
        }
        axf[g_] = ax;
    }

    // ---- LDS init ----
    for (int i = tid; i < 2304; i += 1024) {
        ((int*)h1T)[i] = 0;
        ((int*)h2T)[i] = 0;
    }
    {   // x preload: each half's slice, [t][d][b] f16
        const int htid = tid & 511;
        for (int i = htid; i < TT * 3 * NBH; i += 512) {
            const int t = i / (3 * NBH), rem = i - t * (3 * NBH);
            const int d = rem >> 1, b = rem & 1;
            xs[half][i] = (_Float16)x[(size_t)(b0 + b) * (TT * 3) + t * 3 + d];
        }
    }
    __syncthreads();

    float creg = 0.f;    // A: c1 of (unit 16w+cu, col cb); C: c2 (cb>=2 junk)

    for (int t = 0; t <= TT; ++t) {
        if (group == 0) {
            if (t < TT) {
                f16x8 bx;
                #pragma unroll
                for (int j = 0; j < 8; ++j) bx[j] = (_Float16)0.f;
                if (quad == 0) {
                    const _Float16* xp = xs[half] + t * 6 + (lane & 1);
                    bx[0] = xp[0];
                    bx[1] = xp[2];
                    bx[2] = xp[4];
                }
                const _Float16* hsrc = h1T[half][(t + 1) & 1];
                const f16x8 bh0 = *(const f16x8*)(hsrc + n * HP + quad * 8);
                const f16x8 bh1 = *(const f16x8*)(hsrc + n * HP + quad * 8 + 32);
                f32x4 acc[4];
                #pragma unroll
                for (int g_ = 0; g_ < 4; ++g_) {
                    f32x4 a = __builtin_amdgcn_mfma_f32_16x16x32_f16(axf[g_], bx, biasf[g_], 0, 0, 0);
                    a = __builtin_amdgcn_mfma_f32_16x16x32_f16(whh[g_][0], bh0, a, 0, 0, 0);
                    a = __builtin_amdgcn_mfma_f32_16x16x32_f16(whh[g_][1], bh1, a, 0, 0, 0);
                    acc[g_] = a;
                }
                if (n < NBH) {
                    #pragma unroll
                    for (int r = 0; r < 4; ++r) {
                        const int slot = (16 * quad + 4 * r + n) ^ (quad << 2);
                        f32x4 v = {acc[0][r], acc[1][r], acc[2][r], acc[3][r]};
                        cellA[half][w][slot] = v;
                    }
                }
                const f32x4 gate = cellA[half][w][rdslot];   // cb>=2 lanes: junk
                const float is = sigmoidf_(gate[0]);
                const float fs = sigmoidf_(gate[1]);
                const float gt = tanhf_(gate[2]);
                const float os = sigmoidf_(gate[3]);
                creg = fs * creg + is * gt;
                h1T[half][t & 1][cb * HP + 16 * w + cu] = (_Float16)(os * tanhf_(creg));
            }
        } else {
            if (t >= 1) {
                // fused K=128 matvec over [h1(t-1); h2(t-2)]
                const _Float16* h1src = h1T[half][(t + 1) & 1];
                const _Float16* h2src = h2T[half][(t + 1) & 1];
                const f16x8 b10 = *(const f16x8*)(h1src + n * HP + quad * 8);
                const f16x8 b11 = *(const f16x8*)(h1src + n * HP + quad * 8 + 32);
                const f16x8 b20 = *(const f16x8*)(h2src + n * HP + quad * 8);
                const f16x8 b21 = *(const f16x8*)(h2src + n * HP + quad * 8 + 32);
                f32x4 acc[4];
                #pragma unroll
                for (int g_ = 0; g_ < 4; ++g_) {
                    f32x4 a = __builtin_amdgcn_mfma_f32_16x16x32_f16(wih[g_][0], b10, biasf[g_], 0, 0, 0);
                    a = __builtin_amdgcn_mfma_f32_16x16x32_f16(wih[g_][1], b11, a, 0, 0, 0);
                    a = __builtin_amdgcn_mfma_f32_16x16x32_f16(whh[g_][0], b20, a, 0, 0, 0);
                    a = __builtin_amdgcn_mfma_f32_16x16x32_f16(whh[g_][1], b21, a, 0, 0, 0);
                    acc[g_] = a;
                }
                if (n < NBH) {
                    #pragma unroll
                    for (int r = 0; r < 4; ++r) {
                        const int slot = (16 * quad + 4 * r + n) ^ (quad << 2);
                        f32x4 v = {acc[0][r], acc[1][r], acc[2][r], acc[3][r]};
                        cellC[half][w][slot] = v;
                    }
                }
                const f32x4 gate = cellC[half][w][rdslot];
                const float is = sigmoidf_(gate[0]);
                const float fs = sigmoidf_(gate[1]);
                const float gt = tanhf_(gate[2]);
                const float os = sigmoidf_(gate[3]);
                creg = fs * creg + is * gt;
                const float h = os * tanhf_(creg);
                h2T[half][t & 1][cb * HP + 16 * w + cu] = (_Float16)h;   // h2(t-1)
                if (t == TT) h2f[half][cb * 68 + 16 * w + cu] = h;       // h2(TT-1)
            }
        }
        __syncthreads();
    }

    // ---- epilogue: logits + softmax per half (NBH=2 real batches) ----
    const int htid = tid & 511;
    if (htid < 8) {
        const int b = htid & 1, o = htid >> 1;
        float acc = b_out[o];
        #pragma unroll
        for (int j = 0; j < HH; ++j)
            acc = fmaf(w_out[o * HH + j], h2f[half][b * 68 + j], acc);
        lg[half][b][o] = acc;
    }
    __syncthreads();
    if (htid < NBH) {
        const int b = htid;
        const float l0 = lg[half][b][0], l1 = lg[half][b][1];
        const float l2 = lg[half][b][2], l3 = lg[half][b][3];
        const float m  = fmaxf(fmaxf(l0, l1), fmaxf(l2, l3));
        const float e0 = __expf(l0 - m), e1 = __expf(l1 - m);
        const float e2 = __expf(l2 - m), e3 = __expf(l3 - m);
        const float sum = 1.0f / (e0 + e1 + e2 + e3);
        out[(b0 + b) * 4 + 0] = e0 * sum;
        out[(b0 + b) * 4 + 1] = e1 * sum;
        out[(b0 + b) * 4 + 2] = e2 * sum;
        out[(b0 + b) * 4 + 3] = e3 * sum;
    }
}

extern "C" void kernel_launch(void* const* d_in, const int* in_sizes, int n_in,
                              void* d_out, int out_size, void* d_ws, size_t ws_size,
                              hipStream_t stream) {
    const float* x     = (const float*)d_in[0];
    const float* w_ih0 = (const float*)d_in[1];
    const float* w_hh0 = (const float*)d_in[2];
    const float* b_ih0 = (const float*)d_in[3];
    const float* b_hh0 = (const float*)d_in[4];
    const float* w_ih1 = (const float*)d_in[5];
    const float* w_hh1 = (const float*)d_in[6];
    const float* b_ih1 = (const float*)d_in[7];
    const float* b_hh1 = (const float*)d_in[8];
    const float* w_out = (const float*)d_in[9];
    const float* b_out = (const float*)d_in[10];
    float* out = (float*)d_out;

    hipLaunchKernelGGL(lstm_mfma, dim3(NBLK), dim3(1024), 0, stream,
                       x, w_ih0, w_hh0, b_ih0, b_hh0,
                       w_ih1, w_hh1, b_ih1, b_hh1,
                       w_out, b_out, out);
}

// Round 14
// 764.267 us; speedup vs baseline: 1.1597x; 1.0023x over previous
//
#include <hip/hip_runtime.h>

#define TT    512
#define HH    64
#define NBH   2                  // batches per recurrence
#define NBLK  256                // 256 blocks x 512 threads; 4 batches/block
#define HP    72                 // h^T pitch in f16

typedef _Float16 f16x8 __attribute__((ext_vector_type(8)));
typedef float    f32x4 __attribute__((ext_vector_type(4)));

__device__ __forceinline__ float sigmoidf_(float x) {
    return 1.0f / (1.0f + __expf(-x));
}
__device__ __forceinline__ float tanhf_(float x) {
    return 1.0f - 2.0f / (1.0f + __expf(2.0f * x));
}

// 256 blocks x 512 threads (8 waves, 2/SIMD -> reg cap 256). TWO recurrences
// x 4 waves; each wave runs BOTH layers for its recurrence ("fused wave"):
//   layer-1 chain (3 MFMAs: x-transform + W_hh0 over h1(t-1))   [t < TT]
//   layer-2 chain (4 MFMAs: W_ih1 over h1(t-1), W_hh1 over h2(t-2)) [t >= 1]
// -> each SIMD hosts 2 waves x 2 independent chains = 4 streams (the ILP/TLP
// r12 wanted), WITHOUT the 16-wave 128-reg cap that spilled r12/r13 (134 MB
// scratch traffic from ~4 spilled dwords/lane-tick). r13 lesson: 4 waves/SIMD
// and a ~160-reg working set are structurally incompatible.
// Wave w owns M-tiles {w,w+4,w+8,w+12} (i,f,g,o of units [16w,16w+16) in one
// lane's accs); same-wave cell transpose -> 1 cell per lane PER LAYER
// (2 pointwises/lane). Bias is added POST-transpose (biasA/biasC = 8 scalar
// regs vs 32 in C-layout — the reg trim; pure fp32 add reorder, ~ulp).
// One barrier per tick, ticks 0..TT. Precision: f16 weights/h-hop/x, fp32
// accum/pointwise/c (lineage absmax 3.9e-3).
// Lessons kept: no cross-block handoff (r8), in-WG parallelism only (r10-13).
__global__ __launch_bounds__(512) void lstm_mfma(
    const float* __restrict__ x,
    const float* __restrict__ w_ih0, const float* __restrict__ w_hh0,
    const float* __restrict__ b_ih0, const float* __restrict__ b_hh0,
    const float* __restrict__ w_ih1, const float* __restrict__ w_hh1,
    const float* __restrict__ b_ih1, const float* __restrict__ b_hh1,
    const float* __restrict__ w_out, const float* __restrict__ b_out,
    float* __restrict__ out)
{
    __shared__ __align__(16) _Float16 h1T[2][2][16 * HP];  // [rec][buf]
    __shared__ __align__(16) _Float16 h2T[2][2][16 * HP];
    __shared__ _Float16 xs[2][TT * 3 * NBH];               // [rec] x f16
    __shared__ __align__(16) f32x4 cellA[2][4][64];        // [rec][wave]
    __shared__ __align__(16) f32x4 cellC[2][4][64];
    __shared__ __align__(16) float h2f[2][4 * 68];         // final h2 fp32
    __shared__ float lg[2][NBH][4];

    const int tid  = threadIdx.x;
    const int rec  = tid >> 8;           // 0/1: which recurrence
    const int w    = (tid >> 6) & 3;     // wave-in-recurrence
    const int lane = tid & 63;
    const int quad = lane >> 4;
    const int n    = lane & 15;          // MFMA column
    const int b0   = blockIdx.x * 4 + rec * NBH;

    const int cu    = lane >> 2;                      // unit after transpose
    const int cb    = lane & 3;                       // col after transpose (0..1 real)
    const int rdslot = lane ^ ((lane >> 4) << 2);     // XOR-swizzled cell slot

    // ---- persistent weight fragments: BOTH layers per wave ----
    f16x8 whh0[4][2], wih1[4][2], whh1[4][2], axf[4];
    float biasA[4], biasC[4];
    #pragma unroll
    for (int g_ = 0; g_ < 4; ++g_) {
        const int arow = 16 * w + 64 * g_ + n;        // A-frag row m = lane&15
        #pragma unroll
        for (int k0 = 0; k0 < 2; ++k0) {
            const int off = quad * 8 + 32 * k0;
            #pragma unroll
            for (int j = 0; j < 8; ++j) {
                whh0[g_][k0][j] = (_Float16)w_hh0[arow * HH + off + j];
                wih1[g_][k0][j] = (_Float16)w_ih1[arow * HH + off + j];
                whh1[g_][k0][j] = (_Float16)w_hh1[arow * HH + off + j];
            }
        }
        f16x8 ax;
        #pragma unroll
        for (int j = 0; j < 8; ++j) ax[j] = (_Float16)0.f;
        if (quad == 0) {                              // K=3 x-transform
            ax[0] = (_Float16)w_ih0[arow * 3 + 0];
            ax[1] = (_Float16)w_ih0[arow * 3 + 1];
            ax[2] = (_Float16)w_ih0[arow * 3 + 2];
        }
        axf[g_] = ax;
        // bias for the post-transpose cell this lane owns (unit 16w+cu)
        const int crow = 64 * g_ + 16 * w + cu;
        biasA[g_] = b_ih0[crow] + b_hh0[crow];
        biasC[g_] = b_ih1[crow] + b_hh1[crow];
    }

    // ---- LDS init ----
    for (int i = tid; i < 2304; i += 512) {           // both recs' h buffers
        ((int*)h1T)[i] = 0;
        ((int*)h2T)[i] = 0;
    }
    {   // x preload per recurrence, [t][d][b] f16
        const int htid = tid & 255;
        for (int i = htid; i < TT * 3 * NBH; i += 256) {
            const int t = i / (3 * NBH), rem = i - t * (3 * NBH);
            const int d = rem >> 1, b = rem & 1;
            xs[rec][i] = (_Float16)x[(size_t)(b0 + b) * (TT * 3) + t * 3 + d];
        }
    }
    __syncthreads();

    float c1 = 0.f, c2 = 0.f;            // both layers' c-state, 1 cell each
    const f32x4 zf = {0.f, 0.f, 0.f, 0.f};

    for (int t = 0; t <= TT; ++t) {
        const bool doA = (t < TT);
        const bool doC = (t >= 1);
        f32x4 accA[4], accC[4];

        if (doA) {                        // layer-1 chain: 3 MFMAs
            f16x8 bx;
            #pragma unroll
            for (int j = 0; j < 8; ++j) bx[j] = (_Float16)0.f;
            if (quad == 0) {
                const _Float16* xp = xs[rec] + t * 6 + (lane & 1);
                bx[0] = xp[0];
                bx[1] = xp[2];
                bx[2] = xp[4];
            }
            const _Float16* hs = h1T[rec][(t + 1) & 1];
            const f16x8 a0 = *(const f16x8*)(hs + n * HP + quad * 8);
            const f16x8 a1 = *(const f16x8*)(hs + n * HP + quad * 8 + 32);
            #pragma unroll
            for (int g_ = 0; g_ < 4; ++g_) {
                f32x4 a = __builtin_amdgcn_mfma_f32_16x16x32_f16(axf[g_], bx, zf, 0, 0, 0);
                a = __builtin_amdgcn_mfma_f32_16x16x32_f16(whh0[g_][0], a0, a, 0, 0, 0);
                a = __builtin_amdgcn_mfma_f32_16x16x32_f16(whh0[g_][1], a1, a, 0, 0, 0);
                accA[g_] = a;
            }
        }
        if (doC) {                        // layer-2 chain: 4 MFMAs (K=128)
            const _Float16* h1s = h1T[rec][(t + 1) & 1];
            const _Float16* h2s = h2T[rec][(t + 1) & 1];
            const f16x8 b10 = *(const f16x8*)(h1s + n * HP + quad * 8);
            const f16x8 b11 = *(const f16x8*)(h1s + n * HP + quad * 8 + 32);
            const f16x8 b20 = *(const f16x8*)(h2s + n * HP + quad * 8);
            const f16x8 b21 = *(const f16x8*)(h2s + n * HP + quad * 8 + 32);
            #pragma unroll
            for (int g_ = 0; g_ < 4; ++g_) {
                f32x4 a = __builtin_amdgcn_mfma_f32_16x16x32_f16(wih1[g_][0], b10, zf, 0, 0, 0);
                a = __builtin_amdgcn_mfma_f32_16x16x32_f16(wih1[g_][1], b11, a, 0, 0, 0);
                a = __builtin_amdgcn_mfma_f32_16x16x32_f16(whh1[g_][0], b20, a, 0, 0, 0);
                a = __builtin_amdgcn_mfma_f32_16x16x32_f16(whh1[g_][1], b21, a, 0, 0, 0);
                accC[g_] = a;
            }
        }

        // ---- same-wave transpose (real batch columns only) ----
        if (n < NBH) {
            #pragma unroll
            for (int r = 0; r < 4; ++r) {
                const int slot = (16 * quad + 4 * r + n) ^ (quad << 2);
                if (doA) {
                    f32x4 v = {accA[0][r], accA[1][r], accA[2][r], accA[3][r]};
                    cellA[rec][w][slot] = v;
                }
                if (doC) {
                    f32x4 v = {accC[0][r], accC[1][r], accC[2][r], accC[3][r]};
                    cellC[rec][w][slot] = v;
                }
            }
        }

        // ---- pointwise: 2 cells/lane (bias added here, post-transpose) ----
        if (doA) {
            const f32x4 g = cellA[rec][w][rdslot];
            const float is = sigmoidf_(g[0] + biasA[0]);
            const float fs = sigmoidf_(g[1] + biasA[1]);
            const float gt = tanhf_(g[2] + biasA[2]);
            const float os = sigmoidf_(g[3] + biasA[3]);
            c1 = fs * c1 + is * gt;
            h1T[rec][t & 1][cb * HP + 16 * w + cu] = (_Float16)(os * tanhf_(c1));
        }
        if (doC) {
            const f32x4 g = cellC[rec][w][rdslot];
            const float is = sigmoidf_(g[0] + biasC[0]);
            const float fs = sigmoidf_(g[1] + biasC[1]);
            const float gt = tanhf_(g[2] + biasC[2]);
            const float os = sigmoidf_(g[3] + biasC[3]);
            c2 = fs * c2 + is * gt;
            const float h = os * tanhf_(c2);
            h2T[rec][t & 1][cb * HP + 16 * w + cu] = (_Float16)h;  // h2(t-1)
            if (t == TT) h2f[rec][cb * 68 + 16 * w + cu] = h;      // h2(TT-1)
        }
        __syncthreads();
    }

    // ---- epilogue: logits + softmax per recurrence (NBH=2 batches) ----
    const int htid = tid & 255;
    if (htid < 8) {
        const int b = htid & 1, o = htid >> 1;
        float acc = b_out[o];
        #pragma unroll
        for (int j = 0; j < HH; ++j)
            acc = fmaf(w_out[o * HH + j], h2f[rec][b * 68 + j], acc);
        lg[rec][b][o] = acc;
    }
    __syncthreads();
    if (htid < NBH) {
        const int b = htid;
        const float l0 = lg[rec][b][0], l1 = lg[rec][b][1];
        const float l2 = lg[rec][b][2], l3 = lg[rec][b][3];
        const float m  = fmaxf(fmaxf(l0, l1), fmaxf(l2, l3));
        const float e0 = __expf(l0 - m), e1 = __expf(l1 - m);
        const float e2 = __expf(l2 - m), e3 = __expf(l3 - m);
        const float sum = 1.0f / (e0 + e1 + e2 + e3);
        out[(b0 + b) * 4 + 0] = e0 * sum;
        out[(b0 + b) * 4 + 1] = e1 * sum;
        out[(b0 + b) * 4 + 2] = e2 * sum;
        out[(b0 + b) * 4 + 3] = e3 * sum;
    }
}

extern "C" void kernel_launch(void* const* d_in, const int* in_sizes, int n_in,
                              void* d_out, int out_size, void* d_ws, size_t ws_size,
                              hipStream_t stream) {
    const float* x     = (const float*)d_in[0];
    const float* w_ih0 = (const float*)d_in[1];
    const float* w_hh0 = (const float*)d_in[2];
    const float* b_ih0 = (const float*)d_in[3];
    const float* b_hh0 = (const float*)d_in[4];
    const float* w_ih1 = (const float*)d_in[5];
    const float* w_hh1 = (const float*)d_in[6];
    const float* b_ih1 = (const float*)d_in[7];
    const float* b_hh1 = (const float*)d_in[8];
    const float* w_out = (const float*)d_in[9];
    const float* b_out = (const float*)d_in[10];
    float* out = (float*)d_out;

    hipLaunchKernelGGL(lstm_mfma, dim3(NBLK), dim3(512), 0, stream,
                       x, w_ih0, w_hh0, b_ih0, b_hh0,
                       w_ih1, w_hh1, b_ih1, b_hh1,
                       w_out, b_out, out);
}